// Round 10
// baseline (354.116 us; speedup 1.0000x reference)
//
#include <hip/hip_runtime.h>
#include <math.h>

// Problem constants
#define NHEAD 16
#define MDIM  1024
#define KD    64
#define BATCH 4
#define SEQ   2048
#define MROWS (BATCH*SEQ)   // 8192 rows for all big GEMMs

using short8 = __attribute__((ext_vector_type(8))) short;  // 8 bf16 (4 VGPRs) - MFMA A/B frag
using f4     = __attribute__((ext_vector_type(4))) float;  // MFMA C/D frag (16x16)
using f16x   = __attribute__((ext_vector_type(16))) float; // MFMA C/D frag (32x32)

__device__ inline short f2bf(float x) {
  union { float f; unsigned u; } v; v.f = x;
  unsigned r = v.u + 0x7fffu + ((v.u >> 16) & 1u);  // round-to-nearest-even
  return (short)(r >> 16);
}

// single-instruction RNE pack: two f32 -> two bf16 in one int (lo in low half).
// Bit-identical to f2bf for normal values (both RNE).
__device__ __forceinline__ int cvtpk(float lo, float hi) {
  int r; asm("v_cvt_pk_bf16_f32 %0, %1, %2" : "=v"(r) : "v"(lo), "v"(hi)); return r;
}

// guaranteed single v_exp_f32 (2^x)
__device__ __forceinline__ float fast_exp2(float x) {
#if __has_builtin(__builtin_amdgcn_exp2f)
  return __builtin_amdgcn_exp2f(x);
#else
  return exp2f(x);
#endif
}

// pack two f32 -> bf16 pair in one int (lo in low half) - attn softmax path (unchanged)
__device__ __forceinline__ int pack_bf16(float lo, float hi) {
#if __has_builtin(__builtin_amdgcn_cvt_pk_bf16_f32)
  auto t = __builtin_amdgcn_cvt_pk_bf16_f32(lo, hi);
  int r; __builtin_memcpy(&r, &t, 4); return r;
#else
  unsigned u0 = __float_as_uint(lo) + 0x8000u;
  unsigned u1 = __float_as_uint(hi) + 0x8000u;
  return (int)__builtin_amdgcn_perm(u1, u0, 0x07060302u);  // [bf(hi), bf(lo)]
#endif
}

// async global->LDS, 16B per lane; LDS dest = wave-uniform base + lane*16
__device__ __forceinline__ void g2l16(const void* g, void* l) {
  __builtin_amdgcn_global_load_lds((const __attribute__((address_space(1))) unsigned int*)g,
                                   (__attribute__((address_space(3))) unsigned int*)l, 16, 0, 0);
}

// raw sync primitives for counted-vmcnt pipelining (no compiler vmcnt(0) drains)
#define AHIP_WAIT_LGKM0 asm volatile("s_waitcnt lgkmcnt(0)" ::: "memory")
#define AHIP_WAIT_VM4   asm volatile("s_waitcnt vmcnt(4)" ::: "memory")
#define AHIP_WAIT_VM8   asm volatile("s_waitcnt vmcnt(8)" ::: "memory")
#define AHIP_WAIT_VM0   asm volatile("s_waitcnt vmcnt(0)" ::: "memory")
#define AHIP_SFENCE     __builtin_amdgcn_sched_barrier(0)
#define AHIP_BAR        __builtin_amdgcn_s_barrier()

// ---------------- weight transpose + convert (z-batched): W[1024][1024] f32 -> Wt[n][k] bf16 -----
__global__ void wtrans_kernel(const float* __restrict__ w0, const float* __restrict__ w1,
                              const float* __restrict__ w2, const float* __restrict__ w3,
                              short* __restrict__ o0, short* __restrict__ o1,
                              short* __restrict__ o2, short* __restrict__ o3) {
  int z = blockIdx.z;
  const float* in = z == 0 ? w0 : (z == 1 ? w1 : (z == 2 ? w2 : w3));
  short* out = z == 0 ? o0 : (z == 1 ? o1 : (z == 2 ? o2 : o3));
  __shared__ float t[32][33];
  int bx = blockIdx.x * 32, by = blockIdx.y * 32;
  int tx = threadIdx.x, ty = threadIdx.y;   // (32, 8)
#pragma unroll
  for (int i = 0; i < 4; i++)
    t[ty + i * 8][tx] = in[(size_t)(by + ty + i * 8) * MDIM + bx + tx];
  __syncthreads();
#pragma unroll
  for (int i = 0; i < 4; i++)
    out[(size_t)(bx + ty + i * 8) * MDIM + by + tx] = f2bf(t[tx][ty + i * 8]);
}

// ---------------- 4-wave 128x128 GEMM core (bf16 A via g2l16) - used by gemm_fc ------------------
// 256 threads = 4 waves (2M x 2N), per-wave output 64x64 (acc[4][4]). LDS 64KB -> 2 blocks/CU.
// Per K-tile t: {ds_read 16 frags; lgkmcnt(0); barrier; stage(t+2 -> buf[t&1]); MFMA x32;
// vmcnt(8); barrier}. Counted vmcnt keeps the newest 8-load stage in flight (T3+T4); T5 setprio.
#define G4_PROLOGUE(Ab, Bt)                                                            \
  int tid = threadIdx.x, wid = tid >> 6, lane = tid & 63;                              \
  int quad = lane >> 4, low = lane & 15;                                               \
  int l8 = lane & 7, lr = lane >> 3;                                                   \
  int wrow = (wid >> 1) * 64, wcol = (wid & 1) * 64;                                   \
  const short* aS = Ab + (size_t)(m0 + wid * 32 + lr) * 1024 + (l8 ^ lr) * 8;          \
  const short* bS = Bt + (size_t)(n0 + wid * 32 + lr) * 1024 + (l8 ^ lr) * 8;          \
  auto stage = [&](int t, int b) {                                                     \
    const short* a = aS + t * 64;                                                      \
    const short* bb = bS + t * 64;                                                     \
    short* ad = &As[b][wid * 2048];                                                    \
    short* bd = &Bs[b][wid * 2048];                                                    \
    g2l16(a, ad);                                                                      \
    g2l16(a + 8 * 1024, ad + 512);                                                     \
    g2l16(a + 16 * 1024, ad + 1024);                                                   \
    g2l16(a + 24 * 1024, ad + 1536);                                                   \
    g2l16(bb, bd);                                                                     \
    g2l16(bb + 8 * 1024, bd + 512);                                                    \
    g2l16(bb + 16 * 1024, bd + 1024);                                                  \
    g2l16(bb + 24 * 1024, bd + 1536);                                                  \
  };                                                                                   \
  f4 acc[4][4];                                                                        \
  _Pragma("unroll")                                                                    \
  for (int mf = 0; mf < 4; mf++)                                                       \
    _Pragma("unroll")                                                                  \
    for (int nf = 0; nf < 4; nf++) {                                                   \
      acc[mf][nf][0] = 0.f; acc[mf][nf][1] = 0.f;                                      \
      acc[mf][nf][2] = 0.f; acc[mf][nf][3] = 0.f;                                      \
    }                                                                                  \
  stage(0, 0);                                                                         \
  stage(1, 1);                                                                         \
  AHIP_WAIT_VM8; AHIP_SFENCE; AHIP_BAR; AHIP_SFENCE;

#define G4_MAIN_LOOP()                                                                 \
  for (int t = 0; t < 16; ++t) {                                                       \
    const int cur = t & 1;                                                             \
    short8 af[2][4], bfv[2][4];                                                        \
    _Pragma("unroll")                                                                  \
    for (int kk = 0; kk < 2; kk++) {                                                   \
      _Pragma("unroll")                                                                \
      for (int mf = 0; mf < 4; mf++)                                                   \
        af[kk][mf] = *(const short8*)&As[cur][(wrow + mf * 16 + low) * 64 +            \
                                              (((kk * 4 + quad) ^ (low & 7)) * 8)];    \
      _Pragma("unroll")                                                                \
      for (int nf = 0; nf < 4; nf++)                                                   \
        bfv[kk][nf] = *(const short8*)&Bs[cur][(wcol + nf * 16 + low) * 64 +           \
                                               (((kk * 4 + quad) ^ (low & 7)) * 8)];   \
    }                                                                                  \
    AHIP_WAIT_LGKM0; AHIP_SFENCE;                                                      \
    AHIP_BAR; AHIP_SFENCE;                                                             \
    if (t + 2 < 16) stage(t + 2, cur);                                                 \
    __builtin_amdgcn_s_setprio(1);                                                     \
    _Pragma("unroll")                                                                  \
    for (int kk = 0; kk < 2; kk++)                                                     \
      _Pragma("unroll")                                                                \
      for (int mf = 0; mf < 4; mf++)                                                   \
        _Pragma("unroll")                                                              \
        for (int nf = 0; nf < 4; nf++)                                                 \
          acc[mf][nf] = __builtin_amdgcn_mfma_f32_16x16x32_bf16(af[kk][mf],            \
                          bfv[kk][nf], acc[mf][nf], 0, 0, 0);                          \
    __builtin_amdgcn_s_setprio(0);                                                     \
    AHIP_SFENCE;                                                                       \
    if (t + 2 < 16) { AHIP_WAIT_VM8; } else { AHIP_WAIT_VM0; }                         \
    AHIP_SFENCE; AHIP_BAR; AHIP_SFENCE;                                                \
  }

// ---------------- fused QKV projection GEMM: fp32 A in, cvt folded into staging ------------------
// Replaces the separate cvt_kernel (saved: 96MB fp32 read + 48MB bf16 write pass, ~23us).
// A-side: reg-staged with conversion (T14 async-split): after the mid barrier, issue 8 float4
// loads of the t+2 A-subtile + 4 g2l16 for B; MFMA cluster hides the load latency; then
// v_cvt_pk_bf16_f32 (RNE = bit-identical to old f2bf cvt) + 4 ds_write_b128 into the SAME
// XOR-8-swizzled layout the read side expects: chunk c=lane+64i -> row 8i+(lane>>3),
// slot lane&7, source fp32 chunk (lane&7)^(lane>>3). In-order vmcnt: the wait before the cvt
// (<=4 outstanding) also guarantees the previous tile's B-loads landed (T4 invariant).
// z=0: Qh bf16 [B,H,L,64] scaled by 0.125/ln2;  z=1: Kh same layout;  z=2: Vt bf16 [B,H,64,L]
__launch_bounds__(256, 2)
__global__ void gemm_qkv_kernel(const float* __restrict__ qf32, const float* __restrict__ kf32,
                                const float* __restrict__ vf32, const short* __restrict__ Wqt,
                                const short* __restrict__ Wkt, const short* __restrict__ Wvt,
                                short* __restrict__ Qh, short* __restrict__ Kh,
                                short* __restrict__ Vt) {
  __shared__ __attribute__((aligned(16))) short As[2][128 * 64];
  __shared__ __attribute__((aligned(16))) short Bs[2][128 * 64];
  int z = blockIdx.z;
  const float* Af = z == 0 ? qf32 : (z == 1 ? kf32 : vf32);
  const short* Bt = z == 0 ? Wqt : (z == 1 ? Wkt : Wvt);
  int m0 = blockIdx.x * 128, n0 = blockIdx.y * 128;
  int tid = threadIdx.x, wid = tid >> 6, lane = tid & 63;
  int quad = lane >> 4, low = lane & 15;
  int l8 = lane & 7, lr = lane >> 3;
  int sch = l8 ^ lr;                       // swizzled source chunk (same for all 4 sub-rows)
  int wrow = (wid >> 1) * 64, wcol = (wid & 1) * 64;
  const float* aF = Af + (size_t)(m0 + wid * 32 + lr) * 1024 + sch * 8;
  const short* bS = Bt + (size_t)(n0 + wid * 32 + lr) * 1024 + sch * 8;

  auto stageB = [&](int t, int b) {
    const short* bb = bS + t * 64;
    short* bd = &Bs[b][wid * 2048];
    g2l16(bb, bd);
    g2l16(bb + 8 * 1024, bd + 512);
    g2l16(bb + 16 * 1024, bd + 1024);
    g2l16(bb + 24 * 1024, bd + 1536);
  };

  f4 acc[4][4];
#pragma unroll
  for (int mf = 0; mf < 4; mf++)
#pragma unroll
    for (int nf = 0; nf < 4; nf++) {
      acc[mf][nf][0] = 0.f; acc[mf][nf][1] = 0.f;
      acc[mf][nf][2] = 0.f; acc[mf][nf][3] = 0.f;
    }

  // prologue: stage tiles 0 and 1 (A load+cvt+write inline; B async)
#pragma unroll
  for (int t0 = 0; t0 < 2; ++t0) {
    float4 va[4][2];
#pragma unroll
    for (int i = 0; i < 4; i++) {
      const float4* p = (const float4*)(aF + (size_t)(8 * i) * 1024 + t0 * 64);
      va[i][0] = p[0]; va[i][1] = p[1];
    }
    stageB(t0, t0);
#pragma unroll
    for (int i = 0; i < 4; i++) {
      int4 w = {cvtpk(va[i][0].x, va[i][0].y), cvtpk(va[i][0].z, va[i][0].w),
                cvtpk(va[i][1].x, va[i][1].y), cvtpk(va[i][1].z, va[i][1].w)};
      *(int4*)&As[t0][wid * 2048 + i * 512 + lane * 8] = w;
    }
  }
  AHIP_WAIT_VM0; AHIP_WAIT_LGKM0; AHIP_SFENCE; AHIP_BAR; AHIP_SFENCE;

  for (int t = 0; t < 16; ++t) {
    const int cur = t & 1;
    short8 af[2][4], bfv[2][4];
#pragma unroll
    for (int kk = 0; kk < 2; kk++) {
#pragma unroll
      for (int mf = 0; mf < 4; mf++)
        af[kk][mf] = *(const short8*)&As[cur][(wrow + mf * 16 + low) * 64 +
                                             (((kk * 4 + quad) ^ (low & 7)) * 8)];
#pragma unroll
      for (int nf = 0; nf < 4; nf++)
        bfv[kk][nf] = *(const short8*)&Bs[cur][(wcol + nf * 16 + low) * 64 +
                                              (((kk * 4 + quad) ^ (low & 7)) * 8)];
    }
    AHIP_WAIT_LGKM0; AHIP_SFENCE;
    AHIP_BAR; AHIP_SFENCE;

    float4 va[4][2];
    if (t + 2 < 16) {
#pragma unroll
      for (int i = 0; i < 4; i++) {
        const float4* p = (const float4*)(aF + (size_t)(8 * i) * 1024 + (t + 2) * 64);
        va[i][0] = p[0]; va[i][1] = p[1];
      }
      stageB(t + 2, cur);
    }
    AHIP_SFENCE;

    __builtin_amdgcn_s_setprio(1);
#pragma unroll
    for (int kk = 0; kk < 2; kk++)
#pragma unroll
      for (int mf = 0; mf < 4; mf++)
#pragma unroll
        for (int nf = 0; nf < 4; nf++)
          acc[mf][nf] = __builtin_amdgcn_mfma_f32_16x16x32_bf16(af[kk][mf],
                          bfv[kk][nf], acc[mf][nf], 0, 0, 0);
    __builtin_amdgcn_s_setprio(0);
    AHIP_SFENCE;

    if (t + 2 < 16) {
#pragma unroll
      for (int i = 0; i < 4; i++) {
        int4 w = {cvtpk(va[i][0].x, va[i][0].y), cvtpk(va[i][0].z, va[i][0].w),
                  cvtpk(va[i][1].x, va[i][1].y), cvtpk(va[i][1].z, va[i][1].w)};
        *(int4*)&As[cur][wid * 2048 + i * 512 + lane * 8] = w;
      }
      AHIP_SFENCE;
      AHIP_WAIT_VM4;     // only B(t+2) may remain in flight -> B(t+1) complete (in-order)
    } else {
      AHIP_WAIT_VM0;
    }
    AHIP_SFENCE; AHIP_BAR; AHIP_SFENCE;
  }

  // Q scale folds 1/sqrt(dk) AND 1/ln2 (softmax via exp2)
  float scale = z == 0 ? 0.18033688011112042f : 1.0f;
  short* dst = z == 0 ? Qh : (z == 1 ? Kh : Vt);
#pragma unroll
  for (int mf = 0; mf < 4; mf++)
#pragma unroll
    for (int nf = 0; nf < 4; nf++)
#pragma unroll
      for (int r2 = 0; r2 < 4; r2++) {
        int gr = m0 + wrow + mf * 16 + quad * 4 + r2;
        int gc = n0 + wcol + nf * 16 + low;
        float val = acc[mf][nf][r2];
        int b = gr >> 11, l = gr & 2047, h = gc >> 6, d = gc & 63;
        if (z < 2)
          dst[(((size_t)(b * NHEAD + h)) * SEQ + l) * KD + d] = f2bf(val * scale);
        else
          dst[(((size_t)(b * NHEAD + h)) * KD + d) * SEQ + l] = f2bf(val);
      }
}

// ---------------- FC GEMM: fp32 dst = A*B + bias[n] + res[row,n] ---------------------------------
__launch_bounds__(256, 2)
__global__ void gemm_fc_kernel(const short* __restrict__ Ab, const short* __restrict__ Bt,
                               float* __restrict__ dst, const float* __restrict__ bias,
                               const float* __restrict__ res) {
  __shared__ __attribute__((aligned(16))) short As[2][128 * 64];
  __shared__ __attribute__((aligned(16))) short Bs[2][128 * 64];
  int m0 = blockIdx.x * 128, n0 = blockIdx.y * 128;

  G4_PROLOGUE(Ab, Bt)
  G4_MAIN_LOOP()

#pragma unroll
  for (int mf = 0; mf < 4; mf++)
#pragma unroll
    for (int nf = 0; nf < 4; nf++)
#pragma unroll
      for (int r2 = 0; r2 < 4; r2++) {
        int gr = m0 + wrow + mf * 16 + quad * 4 + r2;
        int gc = n0 + wcol + nf * 16 + low;
        dst[(size_t)gr * 1024 + gc] = acc[mf][nf][r2] + bias[gc] + res[(size_t)gr * 1024 + gc];
      }
}

// ---------------- flash attention: 8 waves x 32q, KVBLK=128, bh->XCD-local grid ------------------
// (unchanged: ~81-85us, FETCH ~25MB ~= ideal, occupancy capped by problem shape)
__launch_bounds__(512, 4)
__global__ void attn_kernel(const short* __restrict__ Qh, const short* __restrict__ Kh,
                            const short* __restrict__ Vt, short* __restrict__ Out) {
  __shared__ __attribute__((aligned(16))) short KT[2][128 * 64];  // 128 keys x 64 d (XOR-8 chunks)
  __shared__ __attribute__((aligned(16))) short VT[2][64 * 128];  // 64 d x 128 keys (XOR-16 chunks)
  int tid = threadIdx.x;
  int wave = tid >> 6, lane = tid & 63;
  int l = lane & 31, hi = lane >> 5;
  int bx = blockIdx.x, by = blockIdx.y;
  int bh = bx + (by & 7) * 8;              // bh % 8 == bx == XCD
  int qc = by >> 3;                        // q-chunk 0..7
  int q0 = qc * 256 + wave * 32;

  const short* Qb = Qh + (size_t)bh * SEQ * KD;
  const short* Kb = Kh + (size_t)bh * SEQ * KD;
  const short* Vb = Vt + (size_t)bh * KD * SEQ;

  int srowK = lane >> 3;                   // 0..7
  int schK = (lane & 7) ^ srowK;
  const short* kS0 = Kb + (size_t)(wave * 16 + srowK) * KD + schK * 8;
  const short* kS1 = kS0 + (size_t)8 * KD;
  int srowV = lane >> 4;                   // 0..3
  int rV0 = wave * 8 + srowV;
  int schV0 = (lane & 15) ^ (rV0 & 15);
  int schV1 = (lane & 15) ^ ((rV0 + 4) & 15);
  const short* vS0 = Vb + (size_t)rV0 * SEQ + schV0 * 8;
  const short* vS1 = Vb + (size_t)(rV0 + 4) * SEQ + schV1 * 8;

  auto stage = [&](int k0, int b) {
    g2l16(kS0 + (size_t)k0 * KD, &KT[b][wave * 1024]);
    g2l16(kS1 + (size_t)k0 * KD, &KT[b][wave * 1024 + 512]);
    g2l16(vS0 + k0, &VT[b][wave * 1024]);
    g2l16(vS1 + k0, &VT[b][wave * 1024 + 512]);
  };

  short8 qf[4];
#pragma unroll
  for (int ks = 0; ks < 4; ks++)
    qf[ks] = *(const short8*)&Qb[(size_t)(q0 + l) * KD + ks * 16 + hi * 8];

  f16x Oacc[2], lacc, fz;
#pragma unroll
  for (int i = 0; i < 16; i++) { Oacc[0][i] = 0.f; Oacc[1][i] = 0.f; lacc[i] = 0.f; fz[i] = 0.f; }
  const short8 onesb = {0x3F80, 0x3F80, 0x3F80, 0x3F80, 0x3F80, 0x3F80, 0x3F80, 0x3F80};  // bf16 1.0

  stage(0, 0);
  __syncthreads();

  for (int c = 0; c < SEQ / 128; c++) {
    int b = c & 1;
    if (c + 1 < SEQ / 128) stage((c + 1) * 128, b ^ 1);

#pragma unroll
    for (int nt = 0; nt < 4; nt++) {
      short8 kf[4];
#pragma unroll
      for (int ks = 0; ks < 4; ks++)
        kf[ks] = *(const short8*)&KT[b][(nt * 32 + l) * 64 + (((ks * 2 + hi) ^ (l & 7)) * 8)];

      f16x S;
      __builtin_amdgcn_s_setprio(1);
      S = __builtin_amdgcn_mfma_f32_32x32x16_bf16(kf[0], qf[0], fz, 0, 0, 0);
      S = __builtin_amdgcn_mfma_f32_32x32x16_bf16(kf[1], qf[1], S, 0, 0, 0);
      S = __builtin_amdgcn_mfma_f32_32x32x16_bf16(kf[2], qf[2], S, 0, 0, 0);
      S = __builtin_amdgcn_mfma_f32_32x32x16_bf16(kf[3], qf[3], S, 0, 0, 0);
      __builtin_amdgcn_s_setprio(0);

      int u[8];
#pragma unroll
      for (int i = 0; i < 8; i++)
        u[i] = pack_bf16(fast_exp2(S[2 * i]), fast_exp2(S[2 * i + 1]));
      asm("v_permlane32_swap_b32 %0, %1" : "+v"(u[0]), "+v"(u[2]));
      asm("v_permlane32_swap_b32 %0, %1" : "+v"(u[1]), "+v"(u[3]));
      asm("v_permlane32_swap_b32 %0, %1" : "+v"(u[4]), "+v"(u[6]));
      asm("v_permlane32_swap_b32 %0, %1" : "+v"(u[5]), "+v"(u[7]));
      short8 pa0, pa1;
      {
        int t0[4] = {u[0], u[1], u[2], u[3]};
        int t1[4] = {u[4], u[5], u[6], u[7]};
        __builtin_memcpy(&pa0, t0, 16);
        __builtin_memcpy(&pa1, t1, 16);
      }

      __builtin_amdgcn_s_setprio(1);
      lacc = __builtin_amdgcn_mfma_f32_32x32x16_bf16(pa0, onesb, lacc, 0, 0, 0);
      lacc = __builtin_amdgcn_mfma_f32_32x32x16_bf16(pa1, onesb, lacc, 0, 0, 0);

#pragma unroll
      for (int dt = 0; dt < 2; dt++) {
        short8 vf0 = *(const short8*)&VT[b][(dt * 32 + l) * 128 + (((nt * 4 + 0 + hi) ^ (l & 15)) * 8)];
        short8 vf1 = *(const short8*)&VT[b][(dt * 32 + l) * 128 + (((nt * 4 + 2 + hi) ^ (l & 15)) * 8)];
        Oacc[dt] = __builtin_amdgcn_mfma_f32_32x32x16_bf16(pa0, vf0, Oacc[dt], 0, 0, 0);
        Oacc[dt] = __builtin_amdgcn_mfma_f32_32x32x16_bf16(pa1, vf1, Oacc[dt], 0, 0, 0);
      }
      __builtin_amdgcn_s_setprio(0);
    }
    __syncthreads();
  }

  int bb = bh >> 4, h = bh & 15;
#pragma unroll
  for (int r = 0; r < 16; r++) {
    int qrow = q0 + (r & 3) + 8 * (r >> 2) + 4 * hi;
    float iv = 1.0f / lacc[r];
#pragma unroll
    for (int dt = 0; dt < 2; dt++) {
      size_t idx = ((size_t)(bb * SEQ + qrow)) * 1024 + h * 64 + dt * 32 + l;
      Out[idx] = f2bf(Oacc[dt][r] * iv);
    }
  }
}

// ---------------- LayerNorm over rows of x[8192][1024] fp32 -> out fp32 ----------------
__launch_bounds__(256)
__global__ void ln_kernel(const float* __restrict__ x, const float* __restrict__ g,
                          const float* __restrict__ b, float* __restrict__ out) {
  int row = blockIdx.x, tid = threadIdx.x;
  const float4* xr = (const float4*)(x + (size_t)row * 1024);
  float4 v = xr[tid];
  float s = v.x + v.y + v.z + v.w;
  float q = v.x * v.x + v.y * v.y + v.z * v.z + v.w * v.w;
#pragma unroll
  for (int o = 32; o > 0; o >>= 1) { s += __shfl_xor(s, o); q += __shfl_xor(q, o); }
  __shared__ float ss[4], sq[4];
  if ((tid & 63) == 0) { ss[tid >> 6] = s; sq[tid >> 6] = q; }
  __syncthreads();
  if (tid == 0) {
    float S = ss[0] + ss[1] + ss[2] + ss[3];
    float Q = sq[0] + sq[1] + sq[2] + sq[3];
    float mean = S * (1.f / 1024.f);
    float var = Q * (1.f / 1024.f) - mean * mean;
    ss[0] = mean; sq[0] = rsqrtf(var + 1e-5f);
  }
  __syncthreads();
  float mean = ss[0], rs = sq[0];
  const float4* g4 = (const float4*)g;
  const float4* b4 = (const float4*)b;
  float4 gg = g4[tid], bb = b4[tid], o;
  o.x = (v.x - mean) * rs * gg.x + bb.x;
  o.y = (v.y - mean) * rs * gg.y + bb.y;
  o.z = (v.z - mean) * rs * gg.z + bb.z;
  o.w = (v.w - mean) * rs * gg.w + bb.w;
  ((float4*)(out + (size_t)row * 1024))[tid] = o;
}

extern "C" void kernel_launch(void* const* d_in, const int* in_sizes, int n_in,
                              void* d_out, int out_size, void* d_ws, size_t ws_size,
                              hipStream_t stream) {
  const float* q   = (const float*)d_in[0];
  const float* k   = (const float*)d_in[1];
  const float* v   = (const float*)d_in[2];
  const float* Wq  = (const float*)d_in[3];
  const float* Wk  = (const float*)d_in[4];
  const float* Wv  = (const float*)d_in[5];
  const float* fcw = (const float*)d_in[6];
  const float* fcb = (const float*)d_in[7];
  const float* lng = (const float*)d_in[8];
  const float* lnb = (const float*)d_in[9];
  float* out = (float*)d_out;

  // workspace layout (72 MiB):
  //  0.. 8 : 4 transposed bf16 weights (2 MiB each)
  //  8..24 : Kh bf16 [B,H,L,64]
  // 24..40 : Vt bf16 [B,H,64,L]
  // 40..56 : Ao bf16 [8192,1024]
  // 56..72 : Qh bf16 [B,H,L,64]
  //  X fp32 [8192,1024] overlays 8..40 (Kh/Vt dead after attention)
  char* ws = (char*)d_ws;
  const size_t MB = 1024 * 1024;
  short* Wqt = (short*)(ws + 0 * MB);
  short* Wkt = (short*)(ws + 2 * MB);
  short* Wvt = (short*)(ws + 4 * MB);
  short* fct = (short*)(ws + 6 * MB);
  short* Kh  = (short*)(ws + 8 * MB);
  short* Vt  = (short*)(ws + 24 * MB);
  short* Ao  = (short*)(ws + 40 * MB);
  short* Qh  = (short*)(ws + 56 * MB);
  float* X   = (float*)(ws + 8 * MB);

  wtrans_kernel<<<dim3(32, 32, 4), dim3(32, 8), 0, stream>>>(Wq, Wk, Wv, fcw, Wqt, Wkt, Wvt, fct);

  gemm_qkv_kernel<<<dim3(64, 8, 3), 256, 0, stream>>>(q, k, v, Wqt, Wkt, Wvt, Qh, Kh, Vt);

  attn_kernel<<<dim3(8, 64), 512, 0, stream>>>(Qh, Kh, Vt, Ao);

  gemm_fc_kernel<<<dim3(64, 8), 256, 0, stream>>>(Ao, fct, X, fcb, q);

  ln_kernel<<<MROWS, 256, 0, stream>>>(X, lng, lnb, out);
}

// Round 11
// 336.248 us; speedup vs baseline: 1.0531x; 1.0531x over previous
//
#include <hip/hip_runtime.h>
#include <math.h>

// Problem constants
#define NHEAD 16
#define MDIM  1024
#define KD    64
#define BATCH 4
#define SEQ   2048
#define MROWS (BATCH*SEQ)   // 8192 rows for all big GEMMs

using short8 = __attribute__((ext_vector_type(8))) short;  // 8 bf16 (4 VGPRs) - MFMA A/B frag
using f4     = __attribute__((ext_vector_type(4))) float;  // MFMA C/D frag (16x16)
using f16x   = __attribute__((ext_vector_type(16))) float; // MFMA C/D frag (32x32)

__device__ inline short f2bf(float x) {
  union { float f; unsigned u; } v; v.f = x;
  unsigned r = v.u + 0x7fffu + ((v.u >> 16) & 1u);  // round-to-nearest-even
  return (short)(r >> 16);
}

// guaranteed single v_exp_f32 (2^x)
__device__ __forceinline__ float fast_exp2(float x) {
#if __has_builtin(__builtin_amdgcn_exp2f)
  return __builtin_amdgcn_exp2f(x);
#else
  return exp2f(x);
#endif
}

// pack two f32 -> bf16 pair in one int (lo in low half)
__device__ __forceinline__ int pack_bf16(float lo, float hi) {
#if __has_builtin(__builtin_amdgcn_cvt_pk_bf16_f32)
  auto t = __builtin_amdgcn_cvt_pk_bf16_f32(lo, hi);
  int r; __builtin_memcpy(&r, &t, 4); return r;
#else
  unsigned u0 = __float_as_uint(lo) + 0x8000u;
  unsigned u1 = __float_as_uint(hi) + 0x8000u;
  return (int)__builtin_amdgcn_perm(u1, u0, 0x07060302u);  // [bf(hi), bf(lo)]
#endif
}

// async global->LDS, 16B per lane; LDS dest = wave-uniform base + lane*16
__device__ __forceinline__ void g2l16(const void* g, void* l) {
  __builtin_amdgcn_global_load_lds((const __attribute__((address_space(1))) unsigned int*)g,
                                   (__attribute__((address_space(3))) unsigned int*)l, 16, 0, 0);
}

// raw sync primitives for counted-vmcnt pipelining (no compiler vmcnt(0) drains)
#define AHIP_WAIT_LGKM0 asm volatile("s_waitcnt lgkmcnt(0)" ::: "memory")
#define AHIP_WAIT_VM4   asm volatile("s_waitcnt vmcnt(4)" ::: "memory")
#define AHIP_WAIT_VM0   asm volatile("s_waitcnt vmcnt(0)" ::: "memory")
#define AHIP_SFENCE     __builtin_amdgcn_sched_barrier(0)
#define AHIP_BAR        __builtin_amdgcn_s_barrier()

// ---------------- weight transpose + convert (z-batched): W[1024][1024] f32 -> Wt[n][k] bf16 -----
__global__ void wtrans_kernel(const float* __restrict__ w0, const float* __restrict__ w1,
                              const float* __restrict__ w2, const float* __restrict__ w3,
                              short* __restrict__ o0, short* __restrict__ o1,
                              short* __restrict__ o2, short* __restrict__ o3) {
  int z = blockIdx.z;
  const float* in = z == 0 ? w0 : (z == 1 ? w1 : (z == 2 ? w2 : w3));
  short* out = z == 0 ? o0 : (z == 1 ? o1 : (z == 2 ? o2 : o3));
  __shared__ float t[32][33];
  int bx = blockIdx.x * 32, by = blockIdx.y * 32;
  int tx = threadIdx.x, ty = threadIdx.y;   // (32, 8)
#pragma unroll
  for (int i = 0; i < 4; i++)
    t[ty + i * 8][tx] = in[(size_t)(by + ty + i * 8) * MDIM + bx + tx];
  __syncthreads();
#pragma unroll
  for (int i = 0; i < 4; i++)
    out[(size_t)(bx + ty + i * 8) * MDIM + by + tx] = f2bf(t[tx][ty + i * 8]);
}

// ---------------- fp32 -> bf16 convert for q,k,v activations ----------------
__global__ void cvt_kernel(const float* __restrict__ q, const float* __restrict__ k,
                           const float* __restrict__ v, short* __restrict__ qb,
                           short* __restrict__ kb, short* __restrict__ vb) {
  const float* in = blockIdx.y == 0 ? q : (blockIdx.y == 1 ? k : v);
  short* out = blockIdx.y == 0 ? qb : (blockIdx.y == 1 ? kb : vb);
  size_t i = (size_t)blockIdx.x * 256 + threadIdx.x;  // one short8 per thread
  float4 a = ((const float4*)in)[2 * i];
  float4 b = ((const float4*)in)[2 * i + 1];
  short8 s = {f2bf(a.x), f2bf(a.y), f2bf(a.z), f2bf(a.w),
              f2bf(b.x), f2bf(b.y), f2bf(b.z), f2bf(b.w)};
  ((short8*)out)[i] = s;
}

// ---------------- 8-wave 128x128 GEMM core, BK=64, counted-vmcnt pipeline, 2 blocks/CU -----------
// A [M][1024] bf16 row-major, B [n][1024] bf16 n-major. 512 threads = 8 waves (2M x 4N),
// per-wave output 64x32 (acc[4][2] 16x16 frags). LDS 64KB: A dbuf 2x16KB, B dbuf 2x16KB ->
// TWO blocks/CU so one block's barrier bubble is filled by the other block's waves.
// Staging: wave w stages A rows [w*16,w*16+16) (2 x g2l16) + B rows [w*16,w*16+16) (2 x g2l16),
// LDS linear dest, source chunk pre-swizzled: slot s of row r holds source 16B chunk s^(r&7).
// Per K-tile t: {ds_read 12 frags; lgkmcnt(0); barrier; stage(t+2 -> buf[t&1]); MFMA x16;
// vmcnt(4); barrier}. Counted vmcnt keeps the newest prefetch in flight across the barrier --
// never drained to 0 in the main loop (T3+T4). setprio(1) around the MFMA cluster (T5).
#define G8_PROLOGUE(Ab, Bt)                                                            \
  int tid = threadIdx.x, wid = tid >> 6, lane = tid & 63;                              \
  int quad = lane >> 4, low = lane & 15;                                               \
  int l8 = lane & 7, lr = lane >> 3;                                                   \
  int wrow = (wid >> 2) * 64, wcol = (wid & 3) * 32;                                   \
  const short* aS = Ab + (size_t)(m0 + wid * 16 + lr) * 1024 + (l8 ^ lr) * 8;          \
  const short* bS = Bt + (size_t)(n0 + wid * 16 + lr) * 1024 + (l8 ^ lr) * 8;          \
  auto stage = [&](int t, int b) {                                                     \
    const short* a = aS + t * 64;                                                      \
    const short* bb = bS + t * 64;                                                     \
    short* ad = &As[b][wid * 1024];                                                    \
    short* bd = &Bs[b][wid * 1024];                                                    \
    g2l16(a, ad);                                                                      \
    g2l16(a + 8 * 1024, ad + 512);                                                     \
    g2l16(bb, bd);                                                                     \
    g2l16(bb + 8 * 1024, bd + 512);                                                    \
  };                                                                                   \
  f4 acc[4][2];                                                                        \
  _Pragma("unroll")                                                                    \
  for (int mf = 0; mf < 4; mf++)                                                       \
    _Pragma("unroll")                                                                  \
    for (int nf = 0; nf < 2; nf++) {                                                   \
      acc[mf][nf][0] = 0.f; acc[mf][nf][1] = 0.f;                                      \
      acc[mf][nf][2] = 0.f; acc[mf][nf][3] = 0.f;                                      \
    }                                                                                  \
  stage(0, 0);                                                                         \
  stage(1, 1);                                                                         \
  AHIP_WAIT_VM4; AHIP_SFENCE; AHIP_BAR; AHIP_SFENCE;

#define G8_MAIN_LOOP()                                                                 \
  for (int t = 0; t < 16; ++t) {                                                       \
    const int cur = t & 1;                                                             \
    short8 af[2][4], bfv[2][2];                                                        \
    _Pragma("unroll")                                                                  \
    for (int kk = 0; kk < 2; kk++) {                                                   \
      _Pragma("unroll")                                                                \
      for (int mf = 0; mf < 4; mf++)                                                   \
        af[kk][mf] = *(const short8*)&As[cur][(wrow + mf * 16 + low) * 64 +            \
                                              (((kk * 4 + quad) ^ (low & 7)) * 8)];    \
      _Pragma("unroll")                                                                \
      for (int nf = 0; nf < 2; nf++)                                                   \
        bfv[kk][nf] = *(const short8*)&Bs[cur][(wcol + nf * 16 + low) * 64 +           \
                                               (((kk * 4 + quad) ^ (low & 7)) * 8)];   \
    }                                                                                  \
    AHIP_WAIT_LGKM0; AHIP_SFENCE;                                                      \
    AHIP_BAR; AHIP_SFENCE;                                                             \
    if (t + 2 < 16) stage(t + 2, cur);                                                 \
    __builtin_amdgcn_s_setprio(1);                                                     \
    _Pragma("unroll")                                                                  \
    for (int kk = 0; kk < 2; kk++)                                                     \
      _Pragma("unroll")                                                                \
      for (int mf = 0; mf < 4; mf++)                                                   \
        _Pragma("unroll")                                                              \
        for (int nf = 0; nf < 2; nf++)                                                 \
          acc[mf][nf] = __builtin_amdgcn_mfma_f32_16x16x32_bf16(af[kk][mf],            \
                          bfv[kk][nf], acc[mf][nf], 0, 0, 0);                          \
    __builtin_amdgcn_s_setprio(0);                                                     \
    AHIP_SFENCE;                                                                       \
    if (t + 2 < 16) { AHIP_WAIT_VM4; } else { AHIP_WAIT_VM0; }                         \
    AHIP_SFENCE; AHIP_BAR; AHIP_SFENCE;                                                \
  }

// ---------------- batched QKV projection GEMM (z selects q/k/v) ----------------------------------
// z=0: Qh bf16 [B,H,L,64] scaled by 0.125/ln2;  z=1: Kh same layout;  z=2: Vt bf16 [B,H,64,L]
__launch_bounds__(512, 4)
__global__ void gemm_qkv_kernel(const short* __restrict__ qb, const short* __restrict__ kb,
                                const short* __restrict__ vb, const short* __restrict__ Wqt,
                                const short* __restrict__ Wkt, const short* __restrict__ Wvt,
                                short* __restrict__ Qh, short* __restrict__ Kh,
                                short* __restrict__ Vt) {
  __shared__ __attribute__((aligned(16))) short As[2][128 * 64];
  __shared__ __attribute__((aligned(16))) short Bs[2][128 * 64];
  int z = blockIdx.z;
  const short* Ab = z == 0 ? qb : (z == 1 ? kb : vb);
  const short* Bt = z == 0 ? Wqt : (z == 1 ? Wkt : Wvt);
  int m0 = blockIdx.x * 128, n0 = blockIdx.y * 128;

  G8_PROLOGUE(Ab, Bt)
  G8_MAIN_LOOP()

  // Q scale folds 1/sqrt(dk) AND 1/ln2 (softmax via exp2)
  float scale = z == 0 ? 0.18033688011112042f : 1.0f;
  short* dst = z == 0 ? Qh : (z == 1 ? Kh : Vt);
#pragma unroll
  for (int mf = 0; mf < 4; mf++)
#pragma unroll
    for (int nf = 0; nf < 2; nf++)
#pragma unroll
      for (int r2 = 0; r2 < 4; r2++) {
        int gr = m0 + wrow + mf * 16 + quad * 4 + r2;
        int gc = n0 + wcol + nf * 16 + low;
        float val = acc[mf][nf][r2];
        int b = gr >> 11, l = gr & 2047, h = gc >> 6, d = gc & 63;
        if (z < 2)
          dst[(((size_t)(b * NHEAD + h)) * SEQ + l) * KD + d] = f2bf(val * scale);
        else
          dst[(((size_t)(b * NHEAD + h)) * KD + d) * SEQ + l] = f2bf(val);
      }
}

// ---------------- FC GEMM: fp32 dst = A*B + bias[n] + res[row,n] ---------------------------------
__launch_bounds__(512, 4)
__global__ void gemm_fc_kernel(const short* __restrict__ Ab, const short* __restrict__ Bt,
                               float* __restrict__ dst, const float* __restrict__ bias,
                               const float* __restrict__ res) {
  __shared__ __attribute__((aligned(16))) short As[2][128 * 64];
  __shared__ __attribute__((aligned(16))) short Bs[2][128 * 64];
  int m0 = blockIdx.x * 128, n0 = blockIdx.y * 128;

  G8_PROLOGUE(Ab, Bt)
  G8_MAIN_LOOP()

#pragma unroll
  for (int mf = 0; mf < 4; mf++)
#pragma unroll
    for (int nf = 0; nf < 2; nf++)
#pragma unroll
      for (int r2 = 0; r2 < 4; r2++) {
        int gr = m0 + wrow + mf * 16 + quad * 4 + r2;
        int gc = n0 + wcol + nf * 16 + low;
        dst[(size_t)gr * 1024 + gc] = acc[mf][nf][r2] + bias[gc] + res[(size_t)gr * 1024 + gc];
      }
}

// ---------------- flash attention: 8 waves x 32q, KVBLK=128, bh->XCD-local grid ------------------
// Qh,Kh bf16 [B,H,L,64] (Q pre-scaled by 0.125/ln2), Vt bf16 [B,H,64,L] -> Out bf16 [B,L,H*64]
// 512 threads = 8 waves x 32 queries (256 q/block). KVBLK=128: 16 chunks, LDS 64KB dbuf
// (KT 2x[128][64] + VT 2x[64][128]) -> 2 blocks/CU, 16 waves/CU. Grid (8,64) with
// bh = bx + (by&7)*8: all 8 q-chunk blocks of a (b,h) land on ONE XCD -> K/V L2-local
// (FETCH 139MB -> 25MB measured, r8). Swapped QK^T (S^T = mfma(K,Q), 32x32x16); softmax
// in-register via cvt_pk + permlane32_swap; denominator on the MFMA pipe (lacc = mfma(P,ones),
// reg<->query mapping matches Oacc) -> shuffle-free finalize.
__launch_bounds__(512, 4)
__global__ void attn_kernel(const short* __restrict__ Qh, const short* __restrict__ Kh,
                            const short* __restrict__ Vt, short* __restrict__ Out) {
  __shared__ __attribute__((aligned(16))) short KT[2][128 * 64];  // 128 keys x 64 d (XOR-8 chunks)
  __shared__ __attribute__((aligned(16))) short VT[2][64 * 128];  // 64 d x 128 keys (XOR-16 chunks)
  int tid = threadIdx.x;
  int wave = tid >> 6, lane = tid & 63;
  int l = lane & 31, hi = lane >> 5;
  int bx = blockIdx.x, by = blockIdx.y;
  int bh = bx + (by & 7) * 8;              // bh % 8 == bx == XCD
  int qc = by >> 3;                        // q-chunk 0..7
  int q0 = qc * 256 + wave * 32;

  const short* Qb = Qh + (size_t)bh * SEQ * KD;
  const short* Kb = Kh + (size_t)bh * SEQ * KD;
  const short* Vb = Vt + (size_t)bh * KD * SEQ;

  int srowK = lane >> 3;                   // 0..7
  int schK = (lane & 7) ^ srowK;
  const short* kS0 = Kb + (size_t)(wave * 16 + srowK) * KD + schK * 8;
  const short* kS1 = kS0 + (size_t)8 * KD;
  int srowV = lane >> 4;                   // 0..3
  int rV0 = wave * 8 + srowV;
  int schV0 = (lane & 15) ^ (rV0 & 15);
  int schV1 = (lane & 15) ^ ((rV0 + 4) & 15);
  const short* vS0 = Vb + (size_t)rV0 * SEQ + schV0 * 8;
  const short* vS1 = Vb + (size_t)(rV0 + 4) * SEQ + schV1 * 8;

  auto stage = [&](int k0, int b) {
    g2l16(kS0 + (size_t)k0 * KD, &KT[b][wave * 1024]);
    g2l16(kS1 + (size_t)k0 * KD, &KT[b][wave * 1024 + 512]);
    g2l16(vS0 + k0, &VT[b][wave * 1024]);
    g2l16(vS1 + k0, &VT[b][wave * 1024 + 512]);
  };

  short8 qf[4];
#pragma unroll
  for (int ks = 0; ks < 4; ks++)
    qf[ks] = *(const short8*)&Qb[(size_t)(q0 + l) * KD + ks * 16 + hi * 8];

  f16x Oacc[2], lacc, fz;
#pragma unroll
  for (int i = 0; i < 16; i++) { Oacc[0][i] = 0.f; Oacc[1][i] = 0.f; lacc[i] = 0.f; fz[i] = 0.f; }
  const short8 onesb = {0x3F80, 0x3F80, 0x3F80, 0x3F80, 0x3F80, 0x3F80, 0x3F80, 0x3F80};  // bf16 1.0

  stage(0, 0);
  __syncthreads();

  for (int c = 0; c < SEQ / 128; c++) {
    int b = c & 1;
    if (c + 1 < SEQ / 128) stage((c + 1) * 128, b ^ 1);

#pragma unroll
    for (int nt = 0; nt < 4; nt++) {
      short8 kf[4];
#pragma unroll
      for (int ks = 0; ks < 4; ks++)
        kf[ks] = *(const short8*)&KT[b][(nt * 32 + l) * 64 + (((ks * 2 + hi) ^ (l & 7)) * 8)];

      f16x S;
      __builtin_amdgcn_s_setprio(1);
      S = __builtin_amdgcn_mfma_f32_32x32x16_bf16(kf[0], qf[0], fz, 0, 0, 0);
      S = __builtin_amdgcn_mfma_f32_32x32x16_bf16(kf[1], qf[1], S, 0, 0, 0);
      S = __builtin_amdgcn_mfma_f32_32x32x16_bf16(kf[2], qf[2], S, 0, 0, 0);
      S = __builtin_amdgcn_mfma_f32_32x32x16_bf16(kf[3], qf[3], S, 0, 0, 0);
      __builtin_amdgcn_s_setprio(0);

      int u[8];
#pragma unroll
      for (int i = 0; i < 8; i++)
        u[i] = pack_bf16(fast_exp2(S[2 * i]), fast_exp2(S[2 * i + 1]));
      asm("v_permlane32_swap_b32 %0, %1" : "+v"(u[0]), "+v"(u[2]));
      asm("v_permlane32_swap_b32 %0, %1" : "+v"(u[1]), "+v"(u[3]));
      asm("v_permlane32_swap_b32 %0, %1" : "+v"(u[4]), "+v"(u[6]));
      asm("v_permlane32_swap_b32 %0, %1" : "+v"(u[5]), "+v"(u[7]));
      short8 pa0, pa1;
      {
        int t0[4] = {u[0], u[1], u[2], u[3]};
        int t1[4] = {u[4], u[5], u[6], u[7]};
        __builtin_memcpy(&pa0, t0, 16);
        __builtin_memcpy(&pa1, t1, 16);
      }

      __builtin_amdgcn_s_setprio(1);
      lacc = __builtin_amdgcn_mfma_f32_32x32x16_bf16(pa0, onesb, lacc, 0, 0, 0);
      lacc = __builtin_amdgcn_mfma_f32_32x32x16_bf16(pa1, onesb, lacc, 0, 0, 0);

#pragma unroll
      for (int dt = 0; dt < 2; dt++) {
        short8 vf0 = *(const short8*)&VT[b][(dt * 32 + l) * 128 + (((nt * 4 + 0 + hi) ^ (l & 15)) * 8)];
        short8 vf1 = *(const short8*)&VT[b][(dt * 32 + l) * 128 + (((nt * 4 + 2 + hi) ^ (l & 15)) * 8)];
        Oacc[dt] = __builtin_amdgcn_mfma_f32_32x32x16_bf16(pa0, vf0, Oacc[dt], 0, 0, 0);
        Oacc[dt] = __builtin_amdgcn_mfma_f32_32x32x16_bf16(pa1, vf1, Oacc[dt], 0, 0, 0);
      }
      __builtin_amdgcn_s_setprio(0);
    }
    __syncthreads();
  }

  int bb = bh >> 4, h = bh & 15;
#pragma unroll
  for (int r = 0; r < 16; r++) {
    int qrow = q0 + (r & 3) + 8 * (r >> 2) + 4 * hi;
    float iv = 1.0f / lacc[r];
#pragma unroll
    for (int dt = 0; dt < 2; dt++) {
      size_t idx = ((size_t)(bb * SEQ + qrow)) * 1024 + h * 64 + dt * 32 + l;
      Out[idx] = f2bf(Oacc[dt][r] * iv);
    }
  }
}

// ---------------- LayerNorm over rows of x[8192][1024] fp32 -> out fp32 ----------------
__launch_bounds__(256)
__global__ void ln_kernel(const float* __restrict__ x, const float* __restrict__ g,
                          const float* __restrict__ b, float* __restrict__ out) {
  int row = blockIdx.x, tid = threadIdx.x;
  const float4* xr = (const float4*)(x + (size_t)row * 1024);
  float4 v = xr[tid];
  float s = v.x + v.y + v.z + v.w;
  float q = v.x * v.x + v.y * v.y + v.z * v.z + v.w * v.w;
#pragma unroll
  for (int o = 32; o > 0; o >>= 1) { s += __shfl_xor(s, o); q += __shfl_xor(q, o); }
  __shared__ float ss[4], sq[4];
  if ((tid & 63) == 0) { ss[tid >> 6] = s; sq[tid >> 6] = q; }
  __syncthreads();
  if (tid == 0) {
    float S = ss[0] + ss[1] + ss[2] + ss[3];
    float Q = sq[0] + sq[1] + sq[2] + sq[3];
    float mean = S * (1.f / 1024.f);
    float var = Q * (1.f / 1024.f) - mean * mean;
    ss[0] = mean; sq[0] = rsqrtf(var + 1e-5f);
  }
  __syncthreads();
  float mean = ss[0], rs = sq[0];
  const float4* g4 = (const float4*)g;
  const float4* b4 = (const float4*)b;
  float4 gg = g4[tid], bb = b4[tid], o;
  o.x = (v.x - mean) * rs * gg.x + bb.x;
  o.y = (v.y - mean) * rs * gg.y + bb.y;
  o.z = (v.z - mean) * rs * gg.z + bb.z;
  o.w = (v.w - mean) * rs * gg.w + bb.w;
  ((float4*)(out + (size_t)row * 1024))[tid] = o;
}

extern "C" void kernel_launch(void* const* d_in, const int* in_sizes, int n_in,
                              void* d_out, int out_size, void* d_ws, size_t ws_size,
                              hipStream_t stream) {
  const float* q   = (const float*)d_in[0];
  const float* k   = (const float*)d_in[1];
  const float* v   = (const float*)d_in[2];
  const float* Wq  = (const float*)d_in[3];
  const float* Wk  = (const float*)d_in[4];
  const float* Wv  = (const float*)d_in[5];
  const float* fcw = (const float*)d_in[6];
  const float* fcb = (const float*)d_in[7];
  const float* lng = (const float*)d_in[8];
  const float* lnb = (const float*)d_in[9];
  float* out = (float*)d_out;

  // workspace layout (72 MiB, 16-MiB slots with liveness-based reuse):
  //  0.. 8 : 4 transposed bf16 weights (2 MiB each)
  //  S1  8..24 : qb bf16      -> then Kh bf16 [B,H,L,64]
  //  S2 24..40 : kb bf16      -> then Vt bf16 [B,H,64,L]
  //  S3 40..56 : vb bf16      -> then Ao bf16 [8192,1024]
  //  S4 56..72 : Qh bf16 [B,H,L,64]
  //  X fp32 [8192,1024] overlays S1+S2 (Kh/Vt dead after attention)
  char* ws = (char*)d_ws;
  const size_t MB = 1024 * 1024;
  short* Wqt = (short*)(ws + 0 * MB);
  short* Wkt = (short*)(ws + 2 * MB);
  short* Wvt = (short*)(ws + 4 * MB);
  short* fct = (short*)(ws + 6 * MB);
  short* qb  = (short*)(ws + 8 * MB);
  short* kb  = (short*)(ws + 24 * MB);
  short* vb  = (short*)(ws + 40 * MB);
  short* Kh  = (short*)(ws + 8 * MB);
  short* Vt  = (short*)(ws + 24 * MB);
  short* Ao  = (short*)(ws + 40 * MB);
  short* Qh  = (short*)(ws + 56 * MB);
  float* X   = (float*)(ws + 8 * MB);

  wtrans_kernel<<<dim3(32, 32, 4), dim3(32, 8), 0, stream>>>(Wq, Wk, Wv, fcw, Wqt, Wkt, Wvt, fct);

  cvt_kernel<<<dim3(MROWS * MDIM / 8 / 256, 3), 256, 0, stream>>>(q, k, v, qb, kb, vb);

  gemm_qkv_kernel<<<dim3(64, 8, 3), 512, 0, stream>>>(qb, kb, vb, Wqt, Wkt, Wvt, Qh, Kh, Vt);

  attn_kernel<<<dim3(8, 64), 512, 0, stream>>>(Qh, Kh, Vt, Ao);

  gemm_fc_kernel<<<dim3(64, 8), 512, 0, stream>>>(Ao, fct, X, fcb, q);

  ln_kernel<<<MROWS, 256, 0, stream>>>(X, lng, lnb, out);
}